// Round 9
// baseline (359.887 us; speedup 1.0000x reference)
//
#include <hip/hip_runtime.h>

typedef __attribute__((ext_vector_type(4))) float f32x4;
typedef __attribute__((ext_vector_type(8))) short s16x8;
typedef __attribute__((ext_vector_type(4))) int i32x4;
typedef __attribute__((ext_vector_type(4))) unsigned short u16x4;

#define NEG_INF_F (-9.0e15f)
#define LOG2E_F 1.44269504088896340736f
#define N_ROWS 8192
#define F_DIM 256

__device__ __forceinline__ unsigned short f2bf(float f) {
    unsigned int u = __builtin_bit_cast(unsigned int, f);
    u += 0x7fffu + ((u >> 16) & 1u);   // round-to-nearest-even
    return (unsigned short)(u >> 16);
}

// ------------- Kernel 0: pack adj (int32 0/1, 256MB) -> bitmask (8MB) ----
__global__ __launch_bounds__(256) void k0_pack(const int* __restrict__ adj,
                                               unsigned* __restrict__ mask32) {
    const int t0 = (int)blockIdx.x * 256 + (int)threadIdx.x;
    const int nt = (int)gridDim.x * 256;
#pragma unroll 1
    for (int w = t0; w < (N_ROWS * N_ROWS / 32); w += nt) {
        const int* p = adj + (size_t)w * 32;
        unsigned m = 0;
#pragma unroll
        for (int i = 0; i < 8; ++i) {
            i32x4 v = *(const i32x4*)(p + i * 4);
            m |= (v[0] > 0 ? 1u : 0u) << (i * 4);
            m |= (v[1] > 0 ? 2u : 0u) << (i * 4);
            m |= (v[2] > 0 ? 4u : 0u) << (i * 4);
            m |= (v[3] > 0 ? 8u : 0u) << (i * 4);
        }
        mask32[w] = m;
    }
}

// ------------- Kernel 1: hT = bf16(x @ W^T)^T  [256][8192] ---------------
__global__ __launch_bounds__(256) void k1_gemm(const float* __restrict__ x,
                                               const float* __restrict__ W,
                                               unsigned short* __restrict__ hT) {
    __shared__ float xT[128][64];
    __shared__ float wT[128][64];
    const int tid = threadIdx.x;
    const int rb = blockIdx.x >> 2, fbk = blockIdx.x & 3;
    const int row0 = rb * 64, f0 = fbk * 64;
    const int rs = tid >> 2, cs = tid & 3;
    const int r0 = (tid & 15) * 4, fc = (tid >> 4) * 4;
    float acc[4][4];
#pragma unroll
    for (int i = 0; i < 4; ++i)
#pragma unroll
        for (int j = 0; j < 4; ++j) acc[i][j] = 0.0f;

#pragma unroll 1
    for (int p = 0; p < 2; ++p) {
        const int kb = p * 128;
        if (p) __syncthreads();
        const float* xrow = x + (size_t)(row0 + rs) * F_DIM + kb + cs * 32;
        const float* wrow = W + (size_t)(f0 + rs) * F_DIM + kb + cs * 32;
#pragma unroll
        for (int i = 0; i < 8; ++i) {
            f32x4 xv = *(const f32x4*)(xrow + i * 4);
            f32x4 wv = *(const f32x4*)(wrow + i * 4);
#pragma unroll
            for (int jj = 0; jj < 4; ++jj) {
                xT[cs * 32 + i * 4 + jj][rs] = xv[jj];
                wT[cs * 32 + i * 4 + jj][rs] = wv[jj];
            }
        }
        __syncthreads();
#pragma unroll 4
        for (int kk = 0; kk < 128; ++kk) {
            f32x4 xv = *(const f32x4*)&xT[kk][r0];
            f32x4 wv = *(const f32x4*)&wT[kk][fc];
#pragma unroll
            for (int i = 0; i < 4; ++i)
#pragma unroll
                for (int j = 0; j < 4; ++j)
                    acc[i][j] = fmaf(xv[i], wv[j], acc[i][j]);
        }
    }
#pragma unroll
    for (int j = 0; j < 4; ++j) {
        u16x4 t;
        t[0] = f2bf(acc[0][j]); t[1] = f2bf(acc[1][j]);
        t[2] = f2bf(acc[2][j]); t[3] = f2bf(acc[3][j]);
        *(u16x4*)(hT + (size_t)(f0 + fc + j) * N_ROWS + row0 + r0) = t;
    }
}

// ------------- Kernel 1a: va1 = W^T a1, va2 = W^T a2 ---------------------
__global__ __launch_bounds__(256) void kva(const float* __restrict__ W,
                                           const float* __restrict__ a,
                                           float* __restrict__ va) {
    const int k = threadIdx.x;              // 0..255
    const int b = blockIdx.x;               // 0: a1, 1: a2
    const float* av = a + b * 256;
    float s0 = 0.f, s1 = 0.f, s2 = 0.f, s3 = 0.f;
#pragma unroll 8
    for (int f = 0; f < 256; f += 4) {
        s0 = fmaf(av[f],     W[(size_t)f * 256 + k],       s0);
        s1 = fmaf(av[f + 1], W[(size_t)(f + 1) * 256 + k], s1);
        s2 = fmaf(av[f + 2], W[(size_t)(f + 2) * 256 + k], s2);
        s3 = fmaf(av[f + 3], W[(size_t)(f + 3) * 256 + k], s3);
    }
    va[b * 256 + k] = (s0 + s1) + (s2 + s3);
}

// ------------- Kernel 1b: s1 = x@va1, s2 = x@va2 (f32) -------------------
__global__ __launch_bounds__(256) void k1b_s(const float* __restrict__ x,
                                             const float* __restrict__ va,
                                             float* __restrict__ s1,
                                             float* __restrict__ s2) {
    const int tid = threadIdx.x, lane = tid & 63, w = tid >> 6;
    f32x4 a1 = *(const f32x4*)(va + lane * 4);
    f32x4 a2 = *(const f32x4*)(va + 256 + lane * 4);
    const int row0 = blockIdx.x * 32 + w * 8;
#pragma unroll 1
    for (int rr = 0; rr < 8; ++rr) {
        const int row = row0 + rr;
        f32x4 hv = *(const f32x4*)(x + (size_t)row * F_DIM + lane * 4);
        float p1 = hv[0] * a1[0] + hv[1] * a1[1] + hv[2] * a1[2] + hv[3] * a1[3];
        float p2 = hv[0] * a2[0] + hv[1] * a2[1] + hv[2] * a2[2] + hv[3] * a2[3];
#pragma unroll
        for (int o = 32; o; o >>= 1) { p1 += __shfl_xor(p1, o); p2 += __shfl_xor(p2, o); }
        if (lane == 0) { s1[row] = p1; s2[row] = p2; }
    }
}

// ------------- Kernel 1c: M[i] = max over unmasked j of s2[j] ------------
// leaky_relu monotone => row max of e = leaky(s1[i] + M[i]), exact in f32.
// grid 2048 blocks x 4 rows (1 wave/row); s2 staged in LDS.
__global__ __launch_bounds__(256) void kmax(const unsigned* __restrict__ mask32,
                                            const float* __restrict__ s2,
                                            float* __restrict__ Mrow) {
    __shared__ float s2l[8192];
    const int tid = threadIdx.x, lane = tid & 63, wv = tid >> 6;
#pragma unroll
    for (int i = 0; i < 8; ++i) {
        const int idx = (i * 256 + tid) * 4;
        *(f32x4*)&s2l[idx] = *(const f32x4*)(s2 + idx);
    }
    __syncthreads();
    const int row = (int)blockIdx.x * 4 + wv;
    const unsigned* __restrict__ mr = mask32 + (size_t)row * 256;
    float vmax = NEG_INF_F;
#pragma unroll 1
    for (int wi = 0; wi < 4; ++wi) {
        const unsigned m = mr[lane * 4 + wi];
        const int kb = (lane * 4 + wi) * 32;
#pragma unroll
        for (int cc = 0; cc < 8; ++cc) {
            const int c = (cc + lane) & 7;          // LDS bank rotation
            f32x4 v = *(const f32x4*)&s2l[kb + c * 4];
            const unsigned sh = (unsigned)(c * 4);
            vmax = fmaxf(vmax, ((m >> (sh + 0)) & 1u) ? v[0] : NEG_INF_F);
            vmax = fmaxf(vmax, ((m >> (sh + 1)) & 1u) ? v[1] : NEG_INF_F);
            vmax = fmaxf(vmax, ((m >> (sh + 2)) & 1u) ? v[2] : NEG_INF_F);
            vmax = fmaxf(vmax, ((m >> (sh + 3)) & 1u) ? v[3] : NEG_INF_F);
        }
    }
#pragma unroll
    for (int o = 32; o; o >>= 1) vmax = fmaxf(vmax, __shfl_xor(vmax, o));
    if (lane == 0) Mrow[row] = vmax;
}

// ------------- Kernel 2: fused masked softmax + PV (exact precomp max) ---
// grid 1024 = 512 row-blocks x 2 feat halves; 256 thr = 4 waves = 4 key-chunks.
// p = exp2((ev - m_row)*log2e), ev = masked ? leaky(si+sj) : NEG_INF (r8-proven
// path: masked-out -> exp2 underflow -> exactly 0). m_row exact => p in (0,1],
// no online tracking, no per-step shfl, linear merge. bA/bB ping-pong pipelines
// the 8x16B hT loads a full half-step ahead of their MFMAs.

#define P_ONE(D, SV, BIT)                                                     \
    { float t_ = si + (SV); t_ = fmaxf(t_, 0.2f * t_);                        \
      D = exp2f(fmaf(((bb_ & (BIT)) ? t_ : NEG_INF_F), LOG2E_F, -mC)); }

#define HALF_STEP(BFR, MW, K)                                                 \
    {                                                                         \
        const f32x4 svA_ = *(const f32x4*)(s2 + (K) + koff);                  \
        const f32x4 svB_ = *(const f32x4*)(s2 + (K) + koff + 4);              \
        const unsigned bb_ = ((MW) >> koff) & 0xffu;                          \
        float p0_, p1_, p2_, p3_, p4_, p5_, p6_, p7_;                         \
        P_ONE(p0_, svA_[0], 1u)   P_ONE(p1_, svA_[1], 2u)                     \
        P_ONE(p2_, svA_[2], 4u)   P_ONE(p3_, svA_[3], 8u)                     \
        P_ONE(p4_, svB_[0], 16u)  P_ONE(p5_, svB_[1], 32u)                    \
        P_ONE(p6_, svB_[2], 64u)  P_ONE(p7_, svB_[3], 128u)                   \
        l_run += ((p0_ + p1_) + (p2_ + p3_)) + ((p4_ + p5_) + (p6_ + p7_));   \
        s16x8 af_;                                                            \
        af_[0] = (short)f2bf(p0_); af_[1] = (short)f2bf(p1_);                 \
        af_[2] = (short)f2bf(p2_); af_[3] = (short)f2bf(p3_);                 \
        af_[4] = (short)f2bf(p4_); af_[5] = (short)f2bf(p5_);                 \
        af_[6] = (short)f2bf(p6_); af_[7] = (short)f2bf(p7_);                 \
        _Pragma("unroll")                                                     \
        for (int nt_ = 0; nt_ < 8; ++nt_)                                     \
            acc[nt_] = __builtin_amdgcn_mfma_f32_16x16x32_bf16(af_, BFR[nt_], acc[nt_], 0, 0, 0); \
    }

__global__ __launch_bounds__(256) void k2_attn(const unsigned* __restrict__ mask32,
                                               const unsigned short* __restrict__ hT,
                                               const float* __restrict__ s1,
                                               const float* __restrict__ s2,
                                               const float* __restrict__ Mrow,
                                               float* __restrict__ out) {
    __shared__ float lbuf[4][16];               // [wc][row]
    __shared__ float accbuf[3][16][132];        // [wc-1][row][feat] (+4 pad)

    const int tid = threadIdx.x;
    const int lane = tid & 63;
    const int wc = tid >> 6;                    // 0..3 key-chunk
    const int lane15 = lane & 15, kg = lane >> 4, koff = kg * 8;
    const int rowblk = (int)blockIdx.x >> 1;
    const int fh = (int)blockIdx.x & 1;
    const int row0 = rowblk * 16;
    const int mrow = row0 + lane15;
    const int fb = fh * 128;
    const int kbase = wc * 2048;                // each wave owns 2048 keys
    const float si = s1[mrow];
    const float tmx = si + Mrow[mrow];
    const float mC = fmaxf(tmx, 0.2f * tmx) * LOG2E_F;   // leaky(si+M)*log2e, exact row max
    const unsigned* __restrict__ mrow32 = mask32 + (size_t)mrow * 256;

    f32x4 acc[8];
#pragma unroll
    for (int nt = 0; nt < 8; ++nt) { f32x4 z = {0.f, 0.f, 0.f, 0.f}; acc[nt] = z; }
    float l_run = 0.0f;

    // 32-bit hT element offsets (SGPR base + voffset form)
    const unsigned vbase = (unsigned)(fb + lane15) * (unsigned)N_ROWS + (unsigned)koff;

    s16x8 bA[8], bB[8];
#pragma unroll
    for (int nt = 0; nt < 8; ++nt)
        bA[nt] = *(const s16x8*)(hT + (vbase + (unsigned)(nt * 16 * N_ROWS) + (unsigned)kbase));
    unsigned mwc = mrow32[kbase >> 5];

#pragma unroll 1
    for (int it = 0; it < 64; it += 2) {
        const int k0 = kbase + it * 32;
        const int k1 = k0 + 32;
        const int k2n = (it + 2 < 64) ? (k0 + 64) : kbase;   // wrap: loaded, unused

        // issue bB loads (for k1) a full half-step before use
#pragma unroll
        for (int nt = 0; nt < 8; ++nt)
            bB[nt] = *(const s16x8*)(hT + (vbase + (unsigned)(nt * 16 * N_ROWS) + (unsigned)k1));
        const unsigned mwn = mrow32[k1 >> 5];

        HALF_STEP(bA, mwc, k0);

        // issue bA loads (for k2n)
#pragma unroll
        for (int nt = 0; nt < 8; ++nt)
            bA[nt] = *(const s16x8*)(hT + (vbase + (unsigned)(nt * 16 * N_ROWS) + (unsigned)k2n));
        mwc = mrow32[k2n >> 5];

        HALF_STEP(bB, mwn, k1);
    }

    // l: reduce across the 4 kg groups of each row (once, after the loop)
    l_run += __shfl_xor(l_run, 16);
    l_run += __shfl_xor(l_run, 32);
    if (kg == 0) lbuf[wc][lane15] = l_run;

    if (wc > 0) {
#pragma unroll
        for (int r = 0; r < 4; ++r)
#pragma unroll
            for (int nt = 0; nt < 8; ++nt)
                accbuf[wc - 1][kg * 4 + r][nt * 16 + lane15] = acc[nt][r];
    }
    __syncthreads();

    if (wc == 0) {
#pragma unroll
        for (int r = 0; r < 4; ++r) {
            const int dr = kg * 4 + r;          // D-layout row this lane owns
            const float lt = (lbuf[0][dr] + lbuf[1][dr]) + (lbuf[2][dr] + lbuf[3][dr]);
            const float inv = 1.0f / lt;
            float* orow_p = out + (size_t)(row0 + dr) * F_DIM + fb + lane15;
#pragma unroll
            for (int nt = 0; nt < 8; ++nt) {
                const float v = acc[nt][r] + accbuf[0][dr][nt * 16 + lane15]
                              + accbuf[1][dr][nt * 16 + lane15]
                              + accbuf[2][dr][nt * 16 + lane15];
                orow_p[nt * 16] = v * inv;
            }
        }
    }
}

extern "C" void kernel_launch(void* const* d_in, const int* in_sizes, int n_in,
                              void* d_out, int out_size, void* d_ws, size_t ws_size,
                              hipStream_t stream) {
    (void)in_sizes; (void)n_in; (void)out_size; (void)ws_size;
    const float* x  = (const float*)d_in[0];
    const int*  adj = (const int*)d_in[1];
    const float* W  = (const float*)d_in[2];
    const float* a  = (const float*)d_in[3];
    float* out = (float*)d_out;
    char* ws = (char*)d_ws;
    // total ws use: 12.13 MB
    unsigned short* hT = (unsigned short*)ws;                       // 4 MB  [256][8192] bf16
    float* s1 = (float*)(ws + (4 << 20));                           // 32 KB
    float* s2 = (float*)(ws + (4 << 20) + (32 << 10));              // 32 KB
    float* va = (float*)(ws + (4 << 20) + (64 << 10));              // 2 KB  [2][256]
    float* Mr = (float*)(ws + (4 << 20) + (96 << 10));              // 32 KB [8192]
    unsigned* mk = (unsigned*)(ws + (4 << 20) + (128 << 10));       // 8 MB [8192][256] u32

    k0_pack<<<2048, 256, 0, stream>>>(adj, mk);
    k1_gemm<<<512, 256, 0, stream>>>(x, W, hT);
    kva<<<2, 256, 0, stream>>>(W, a, va);
    k1b_s<<<256, 256, 0, stream>>>(x, va, s1, s2);
    kmax<<<2048, 256, 0, stream>>>(mk, s2, Mr);
    k2_attn<<<1024, 256, 0, stream>>>(mk, hT, s1, s2, Mr, out);
}

// Round 10
// 229.234 us; speedup vs baseline: 1.5700x; 1.5700x over previous
//
#include <hip/hip_runtime.h>

typedef __attribute__((ext_vector_type(4))) float f32x4;
typedef __attribute__((ext_vector_type(8))) short s16x8;
typedef __attribute__((ext_vector_type(4))) int i32x4;
typedef __attribute__((ext_vector_type(4))) unsigned short u16x4;

#define NEG_INF_F (-9.0e15f)
#define LOG2E_F 1.44269504088896340736f
#define N_ROWS 8192
#define F_DIM 256

__device__ __forceinline__ unsigned short f2bf(float f) {
    unsigned int u = __builtin_bit_cast(unsigned int, f);
    u += 0x7fffu + ((u >> 16) & 1u);   // round-to-nearest-even
    return (unsigned short)(u >> 16);
}

// ------------- Kernel 0: pack adj (int32 0/1, 256MB) -> bitmask (8MB) ----
__global__ __launch_bounds__(256) void k0_pack(const int* __restrict__ adj,
                                               unsigned* __restrict__ mask32) {
    const int t0 = (int)blockIdx.x * 256 + (int)threadIdx.x;
    const int nt = (int)gridDim.x * 256;
#pragma unroll 1
    for (int w = t0; w < (N_ROWS * N_ROWS / 32); w += nt) {
        const int* p = adj + (size_t)w * 32;
        unsigned m = 0;
#pragma unroll
        for (int i = 0; i < 8; ++i) {
            i32x4 v = *(const i32x4*)(p + i * 4);
            m |= (v[0] > 0 ? 1u : 0u) << (i * 4);
            m |= (v[1] > 0 ? 2u : 0u) << (i * 4);
            m |= (v[2] > 0 ? 4u : 0u) << (i * 4);
            m |= (v[3] > 0 ? 8u : 0u) << (i * 4);
        }
        mask32[w] = m;
    }
}

// ------------- Kernel 1: hTp = bf16(x @ W^T), packed [k/8][feat][k%8] ----
// Packed layout: element (feat f, key k) at (k>>3)*2048 + f*8 + (k&7).
// k2's B-fragment loads become 16-lane-contiguous 256B segments.
__global__ __launch_bounds__(256) void k1_gemm(const float* __restrict__ x,
                                               const float* __restrict__ W,
                                               unsigned short* __restrict__ hTp) {
    __shared__ float xT[128][64];
    __shared__ float wT[128][64];
    const int tid = threadIdx.x;
    const int rb = blockIdx.x >> 2, fbk = blockIdx.x & 3;
    const int row0 = rb * 64, f0 = fbk * 64;
    const int rs = tid >> 2, cs = tid & 3;
    const int r0 = (tid & 15) * 4, fc = (tid >> 4) * 4;
    float acc[4][4];
#pragma unroll
    for (int i = 0; i < 4; ++i)
#pragma unroll
        for (int j = 0; j < 4; ++j) acc[i][j] = 0.0f;

#pragma unroll 1
    for (int p = 0; p < 2; ++p) {
        const int kb = p * 128;
        if (p) __syncthreads();
        const float* xrow = x + (size_t)(row0 + rs) * F_DIM + kb + cs * 32;
        const float* wrow = W + (size_t)(f0 + rs) * F_DIM + kb + cs * 32;
#pragma unroll
        for (int i = 0; i < 8; ++i) {
            f32x4 xv = *(const f32x4*)(xrow + i * 4);
            f32x4 wv = *(const f32x4*)(wrow + i * 4);
#pragma unroll
            for (int jj = 0; jj < 4; ++jj) {
                xT[cs * 32 + i * 4 + jj][rs] = xv[jj];
                wT[cs * 32 + i * 4 + jj][rs] = wv[jj];
            }
        }
        __syncthreads();
#pragma unroll 4
        for (int kk = 0; kk < 128; ++kk) {
            f32x4 xv = *(const f32x4*)&xT[kk][r0];
            f32x4 wv = *(const f32x4*)&wT[kk][fc];
#pragma unroll
            for (int i = 0; i < 4; ++i)
#pragma unroll
                for (int j = 0; j < 4; ++j)
                    acc[i][j] = fmaf(xv[i], wv[j], acc[i][j]);
        }
    }
    // packed write: keys row0+r0..+4 share one 8-key block (r0%8 in {0,4})
    const int kblk = (row0 + r0) >> 3, kslot = (row0 + r0) & 7;
#pragma unroll
    for (int j = 0; j < 4; ++j) {
        u16x4 t;
        t[0] = f2bf(acc[0][j]); t[1] = f2bf(acc[1][j]);
        t[2] = f2bf(acc[2][j]); t[3] = f2bf(acc[3][j]);
        *(u16x4*)(hTp + (size_t)kblk * 2048 + (f0 + fc + j) * 8 + kslot) = t;
    }
}

// ------------- Kernel 1a: va1 = W^T a1, va2 = W^T a2 ---------------------
__global__ __launch_bounds__(256) void kva(const float* __restrict__ W,
                                           const float* __restrict__ a,
                                           float* __restrict__ va) {
    const int k = threadIdx.x;
    const int b = blockIdx.x;
    const float* av = a + b * 256;
    float s0 = 0.f, s1 = 0.f, s2 = 0.f, s3 = 0.f;
#pragma unroll 8
    for (int f = 0; f < 256; f += 4) {
        s0 = fmaf(av[f],     W[(size_t)f * 256 + k],       s0);
        s1 = fmaf(av[f + 1], W[(size_t)(f + 1) * 256 + k], s1);
        s2 = fmaf(av[f + 2], W[(size_t)(f + 2) * 256 + k], s2);
        s3 = fmaf(av[f + 3], W[(size_t)(f + 3) * 256 + k], s3);
    }
    va[b * 256 + k] = (s0 + s1) + (s2 + s3);
}

// ------------- Kernel 1b: s1 = x@va1, s2 = x@va2 (f32) -------------------
__global__ __launch_bounds__(256) void k1b_s(const float* __restrict__ x,
                                             const float* __restrict__ va,
                                             float* __restrict__ s1,
                                             float* __restrict__ s2) {
    const int tid = threadIdx.x, lane = tid & 63, w = tid >> 6;
    f32x4 a1 = *(const f32x4*)(va + lane * 4);
    f32x4 a2 = *(const f32x4*)(va + 256 + lane * 4);
    const int row0 = blockIdx.x * 32 + w * 8;
#pragma unroll 1
    for (int rr = 0; rr < 8; ++rr) {
        const int row = row0 + rr;
        f32x4 hv = *(const f32x4*)(x + (size_t)row * F_DIM + lane * 4);
        float p1 = hv[0] * a1[0] + hv[1] * a1[1] + hv[2] * a1[2] + hv[3] * a1[3];
        float p2 = hv[0] * a2[0] + hv[1] * a2[1] + hv[2] * a2[2] + hv[3] * a2[3];
#pragma unroll
        for (int o = 32; o; o >>= 1) { p1 += __shfl_xor(p1, o); p2 += __shfl_xor(p2, o); }
        if (lane == 0) { s1[row] = p1; s2[row] = p2; }
    }
}

// ------------- Kernel 1c: M[i] = max over unmasked j of s2[j] ------------
__global__ __launch_bounds__(256) void kmax(const unsigned* __restrict__ mask32,
                                            const float* __restrict__ s2,
                                            float* __restrict__ Mrow) {
    __shared__ float s2l[8192];
    const int tid = threadIdx.x, lane = tid & 63, wv = tid >> 6;
#pragma unroll
    for (int i = 0; i < 8; ++i) {
        const int idx = (i * 256 + tid) * 4;
        *(f32x4*)&s2l[idx] = *(const f32x4*)(s2 + idx);
    }
    __syncthreads();
    const int row = (int)blockIdx.x * 4 + wv;
    const unsigned* __restrict__ mr = mask32 + (size_t)row * 256;
    float vmax = NEG_INF_F;
#pragma unroll 1
    for (int wi = 0; wi < 4; ++wi) {
        const unsigned m = mr[lane * 4 + wi];
        const int kb = (lane * 4 + wi) * 32;
#pragma unroll
        for (int cc = 0; cc < 8; ++cc) {
            const int c = (cc + lane) & 7;
            f32x4 v = *(const f32x4*)&s2l[kb + c * 4];
            const unsigned sh = (unsigned)(c * 4);
            vmax = fmaxf(vmax, ((m >> (sh + 0)) & 1u) ? v[0] : NEG_INF_F);
            vmax = fmaxf(vmax, ((m >> (sh + 1)) & 1u) ? v[1] : NEG_INF_F);
            vmax = fmaxf(vmax, ((m >> (sh + 2)) & 1u) ? v[2] : NEG_INF_F);
            vmax = fmaxf(vmax, ((m >> (sh + 3)) & 1u) ? v[3] : NEG_INF_F);
        }
    }
#pragma unroll
    for (int o = 32; o; o >>= 1) vmax = fmaxf(vmax, __shfl_xor(vmax, o));
    if (lane == 0) Mrow[row] = vmax;
}

// ------------- Kernel 2: fused masked softmax + PV -----------------------
// grid 512 = 256 row-blocks(32 rows) x 2 feat halves; 4 waves = 4 key-chunks.
// TWO row-groups per wave share each B-fragment load (halves hT traffic);
// packed hTp layout makes every bfr load 16-lane-contiguous (256B segments).
// Numerics identical to r9 (exact precomp max, exp2 underflow masking).

#define P_ONE(D, SV, BIT, SI, MC)                                             \
    { float t_ = (SI) + (SV); t_ = fmaxf(t_, 0.2f * t_);                      \
      D = exp2f(fmaf(((bb_ & (BIT)) ? t_ : NEG_INF_F), LOG2E_F, -(MC))); }

#define RG_STEP(ACC, BFR, MW, SI, MC, LRUN)                                   \
    {                                                                         \
        const unsigned bb_ = ((MW) >> koff) & 0xffu;                          \
        float p0_, p1_, p2_, p3_, p4_, p5_, p6_, p7_;                         \
        P_ONE(p0_, svA_[0], 1u, SI, MC)   P_ONE(p1_, svA_[1], 2u, SI, MC)     \
        P_ONE(p2_, svA_[2], 4u, SI, MC)   P_ONE(p3_, svA_[3], 8u, SI, MC)     \
        P_ONE(p4_, svB_[0], 16u, SI, MC)  P_ONE(p5_, svB_[1], 32u, SI, MC)    \
        P_ONE(p6_, svB_[2], 64u, SI, MC)  P_ONE(p7_, svB_[3], 128u, SI, MC)   \
        LRUN += ((p0_ + p1_) + (p2_ + p3_)) + ((p4_ + p5_) + (p6_ + p7_));    \
        s16x8 af_;                                                            \
        af_[0] = (short)f2bf(p0_); af_[1] = (short)f2bf(p1_);                 \
        af_[2] = (short)f2bf(p2_); af_[3] = (short)f2bf(p3_);                 \
        af_[4] = (short)f2bf(p4_); af_[5] = (short)f2bf(p5_);                 \
        af_[6] = (short)f2bf(p6_); af_[7] = (short)f2bf(p7_);                 \
        _Pragma("unroll")                                                     \
        for (int nt_ = 0; nt_ < 8; ++nt_)                                     \
            ACC[nt_] = __builtin_amdgcn_mfma_f32_16x16x32_bf16(af_, BFR[nt_], ACC[nt_], 0, 0, 0); \
    }

#define HALF_STEP(BFR, MWA, MWB, K)                                           \
    {                                                                         \
        const f32x4 svA_ = *(const f32x4*)(s2 + (K) + koff);                  \
        const f32x4 svB_ = *(const f32x4*)(s2 + (K) + koff + 4);              \
        RG_STEP(accA, BFR, MWA, siA, mCA, lA)                                 \
        RG_STEP(accB, BFR, MWB, siB, mCB, lB)                                 \
    }

#define LOAD_B(DST, K)                                                        \
    _Pragma("unroll")                                                         \
    for (int nt_ = 0; nt_ < 8; ++nt_)                                         \
        DST[nt_] = *(const s16x8*)(hTp + (unsigned)(((K) >> 3) + kg) * 2048u + vb + (unsigned)(nt_ * 128));

__global__ __launch_bounds__(256) void k2_attn(const unsigned* __restrict__ mask32,
                                               const unsigned short* __restrict__ hTp,
                                               const float* __restrict__ s1,
                                               const float* __restrict__ s2,
                                               const float* __restrict__ Mrow,
                                               float* __restrict__ out) {
    __shared__ float lbuf[4][2][16];            // [wc][rg][row]
    __shared__ float accbuf[3][16][132];        // [wc-1][row][feat] (+4 pad)

    const int tid = threadIdx.x;
    const int lane = tid & 63;
    const int wc = tid >> 6;                    // 0..3 key-chunk
    const int lane15 = lane & 15, kg = lane >> 4, koff = kg * 8;
    const int rowblk = (int)blockIdx.x >> 1;
    const int fh = (int)blockIdx.x & 1;
    const int row0 = rowblk * 32;
    const int mrowA = row0 + lane15, mrowB = row0 + 16 + lane15;
    const int fb = fh * 128;
    const int kbase = wc * 2048;
    const float siA = s1[mrowA], siB = s1[mrowB];
    const float tmxA = siA + Mrow[mrowA], tmxB = siB + Mrow[mrowB];
    const float mCA = fmaxf(tmxA, 0.2f * tmxA) * LOG2E_F;
    const float mCB = fmaxf(tmxB, 0.2f * tmxB) * LOG2E_F;
    const unsigned* __restrict__ mA32 = mask32 + (size_t)mrowA * 256;
    const unsigned* __restrict__ mB32 = mask32 + (size_t)mrowB * 256;

    f32x4 accA[8], accB[8];
#pragma unroll
    for (int nt = 0; nt < 8; ++nt) {
        f32x4 z = {0.f, 0.f, 0.f, 0.f};
        accA[nt] = z; accB[nt] = z;
    }
    float lA = 0.0f, lB = 0.0f;

    const unsigned vb = (unsigned)(fb + lane15) * 8u;

    s16x8 bA[8], bB[8];
    LOAD_B(bA, kbase)
    unsigned mwA = mA32[kbase >> 5], mwB = mB32[kbase >> 5];

#pragma unroll 1
    for (int it = 0; it < 64; it += 2) {
        const int k0 = kbase + it * 32;
        const int k1 = k0 + 32;
        const int k2n = (it + 2 < 64) ? (k0 + 64) : kbase;   // wrap: loaded, unused

        LOAD_B(bB, k1)
        const unsigned mwnA = mA32[k1 >> 5], mwnB = mB32[k1 >> 5];

        HALF_STEP(bA, mwA, mwB, k0);

        LOAD_B(bA, k2n)
        mwA = mA32[k2n >> 5]; mwB = mB32[k2n >> 5];

        HALF_STEP(bB, mwnA, mwnB, k1);
    }

    // l: reduce across the 4 kg groups of each row
    lA += __shfl_xor(lA, 16); lA += __shfl_xor(lA, 32);
    lB += __shfl_xor(lB, 16); lB += __shfl_xor(lB, 32);
    if (kg == 0) { lbuf[wc][0][lane15] = lA; lbuf[wc][1][lane15] = lB; }

    // ---- phase A: merge + write row-group 0 ----
    if (wc > 0) {
#pragma unroll
        for (int r = 0; r < 4; ++r)
#pragma unroll
            for (int nt = 0; nt < 8; ++nt)
                accbuf[wc - 1][kg * 4 + r][nt * 16 + lane15] = accA[nt][r];
    }
    __syncthreads();
    if (wc == 0) {
#pragma unroll
        for (int r = 0; r < 4; ++r) {
            const int dr = kg * 4 + r;
            const float lt = (lbuf[0][0][dr] + lbuf[1][0][dr]) + (lbuf[2][0][dr] + lbuf[3][0][dr]);
            const float inv = 1.0f / lt;
            float* orow_p = out + (size_t)(row0 + dr) * F_DIM + fb + lane15;
#pragma unroll
            for (int nt = 0; nt < 8; ++nt) {
                const float v = accA[nt][r] + accbuf[0][dr][nt * 16 + lane15]
                              + accbuf[1][dr][nt * 16 + lane15]
                              + accbuf[2][dr][nt * 16 + lane15];
                orow_p[nt * 16] = v * inv;
            }
        }
    }
    __syncthreads();

    // ---- phase B: merge + write row-group 1 ----
    if (wc > 0) {
#pragma unroll
        for (int r = 0; r < 4; ++r)
#pragma unroll
            for (int nt = 0; nt < 8; ++nt)
                accbuf[wc - 1][kg * 4 + r][nt * 16 + lane15] = accB[nt][r];
    }
    __syncthreads();
    if (wc == 0) {
#pragma unroll
        for (int r = 0; r < 4; ++r) {
            const int dr = kg * 4 + r;
            const float lt = (lbuf[0][1][dr] + lbuf[1][1][dr]) + (lbuf[2][1][dr] + lbuf[3][1][dr]);
            const float inv = 1.0f / lt;
            float* orow_p = out + (size_t)(row0 + 16 + dr) * F_DIM + fb + lane15;
#pragma unroll
            for (int nt = 0; nt < 8; ++nt) {
                const float v = accB[nt][r] + accbuf[0][dr][nt * 16 + lane15]
                              + accbuf[1][dr][nt * 16 + lane15]
                              + accbuf[2][dr][nt * 16 + lane15];
                orow_p[nt * 16] = v * inv;
            }
        }
    }
}

extern "C" void kernel_launch(void* const* d_in, const int* in_sizes, int n_in,
                              void* d_out, int out_size, void* d_ws, size_t ws_size,
                              hipStream_t stream) {
    (void)in_sizes; (void)n_in; (void)out_size; (void)ws_size;
    const float* x  = (const float*)d_in[0];
    const int*  adj = (const int*)d_in[1];
    const float* W  = (const float*)d_in[2];
    const float* a  = (const float*)d_in[3];
    float* out = (float*)d_out;
    char* ws = (char*)d_ws;
    // total ws use: 12.13 MB
    unsigned short* hTp = (unsigned short*)ws;                      // 4 MB  packed bf16
    float* s1 = (float*)(ws + (4 << 20));                           // 32 KB
    float* s2 = (float*)(ws + (4 << 20) + (32 << 10));              // 32 KB
    float* va = (float*)(ws + (4 << 20) + (64 << 10));              // 2 KB
    float* Mr = (float*)(ws + (4 << 20) + (96 << 10));              // 32 KB
    unsigned* mk = (unsigned*)(ws + (4 << 20) + (128 << 10));       // 8 MB

    k0_pack<<<2048, 256, 0, stream>>>(adj, mk);
    k1_gemm<<<512, 256, 0, stream>>>(x, W, hTp);
    kva<<<2, 256, 0, stream>>>(W, a, va);
    k1b_s<<<256, 256, 0, stream>>>(x, va, s1, s2);
    kmax<<<2048, 256, 0, stream>>>(mk, s2, Mr);
    k2_attn<<<512, 256, 0, stream>>>(mk, hTp, s1, s2, Mr, out);
}

// Round 11
// 180.125 us; speedup vs baseline: 1.9980x; 1.2726x over previous
//
#include <hip/hip_runtime.h>
#include <hip/hip_bf16.h>

typedef __attribute__((ext_vector_type(4))) float f32x4;
typedef __attribute__((ext_vector_type(8))) short s16x8;
typedef __attribute__((ext_vector_type(4))) int i32x4;
typedef __attribute__((ext_vector_type(4))) unsigned short u16x4;

#define NEG_INF_F (-9.0e15f)
#define LOG2E_F 1.44269504088896340736f
#define N_ROWS 8192
#define F_DIM 256

__device__ __forceinline__ unsigned short f2bf(float f) {
    unsigned int u = __builtin_bit_cast(unsigned int, f);
    u += 0x7fffu + ((u >> 16) & 1u);   // round-to-nearest-even
    return (unsigned short)(u >> 16);
}

__device__ __forceinline__ float fast_exp2(float x) {
#if __has_builtin(__builtin_amdgcn_exp2f)
    return __builtin_amdgcn_exp2f(x);   // raw v_exp_f32 (1 ULP); big-neg -> 0.0
#else
    return exp2f(x);
#endif
}

__device__ __forceinline__ short f2bf_fast(float f) {
    __hip_bfloat16 b = __float2bfloat16(f);   // native cast -> v_cvt_pk_bf16_f32 pairs
    return __builtin_bit_cast(short, b);
}

// ------------- Kernel 0: pack adj (int32 0/1, 256MB) -> bitmask (8MB) ----
__global__ __launch_bounds__(256) void k0_pack(const int* __restrict__ adj,
                                               unsigned* __restrict__ mask32) {
    const int t0 = (int)blockIdx.x * 256 + (int)threadIdx.x;
    const int nt = (int)gridDim.x * 256;
#pragma unroll 1
    for (int w = t0; w < (N_ROWS * N_ROWS / 32); w += nt) {
        const int* p = adj + (size_t)w * 32;
        unsigned m = 0;
#pragma unroll
        for (int i = 0; i < 8; ++i) {
            i32x4 v = *(const i32x4*)(p + i * 4);
            m |= (v[0] > 0 ? 1u : 0u) << (i * 4);
            m |= (v[1] > 0 ? 2u : 0u) << (i * 4);
            m |= (v[2] > 0 ? 4u : 0u) << (i * 4);
            m |= (v[3] > 0 ? 8u : 0u) << (i * 4);
        }
        mask32[w] = m;
    }
}

// ------------- Kernel 1: hTp = bf16(x @ W^T), packed [k/8][feat][k%8] ----
__global__ __launch_bounds__(256) void k1_gemm(const float* __restrict__ x,
                                               const float* __restrict__ W,
                                               unsigned short* __restrict__ hTp) {
    __shared__ float xT[128][64];
    __shared__ float wT[128][64];
    const int tid = threadIdx.x;
    const int rb = blockIdx.x >> 2, fbk = blockIdx.x & 3;
    const int row0 = rb * 64, f0 = fbk * 64;
    const int rs = tid >> 2, cs = tid & 3;
    const int r0 = (tid & 15) * 4, fc = (tid >> 4) * 4;
    float acc[4][4];
#pragma unroll
    for (int i = 0; i < 4; ++i)
#pragma unroll
        for (int j = 0; j < 4; ++j) acc[i][j] = 0.0f;

#pragma unroll 1
    for (int p = 0; p < 2; ++p) {
        const int kb = p * 128;
        if (p) __syncthreads();
        const float* xrow = x + (size_t)(row0 + rs) * F_DIM + kb + cs * 32;
        const float* wrow = W + (size_t)(f0 + rs) * F_DIM + kb + cs * 32;
#pragma unroll
        for (int i = 0; i < 8; ++i) {
            f32x4 xv = *(const f32x4*)(xrow + i * 4);
            f32x4 wv = *(const f32x4*)(wrow + i * 4);
#pragma unroll
            for (int jj = 0; jj < 4; ++jj) {
                xT[cs * 32 + i * 4 + jj][rs] = xv[jj];
                wT[cs * 32 + i * 4 + jj][rs] = wv[jj];
            }
        }
        __syncthreads();
#pragma unroll 4
        for (int kk = 0; kk < 128; ++kk) {
            f32x4 xv = *(const f32x4*)&xT[kk][r0];
            f32x4 wv = *(const f32x4*)&wT[kk][fc];
#pragma unroll
            for (int i = 0; i < 4; ++i)
#pragma unroll
                for (int j = 0; j < 4; ++j)
                    acc[i][j] = fmaf(xv[i], wv[j], acc[i][j]);
        }
    }
    const int kblk = (row0 + r0) >> 3, kslot = (row0 + r0) & 7;
#pragma unroll
    for (int j = 0; j < 4; ++j) {
        u16x4 t;
        t[0] = f2bf(acc[0][j]); t[1] = f2bf(acc[1][j]);
        t[2] = f2bf(acc[2][j]); t[3] = f2bf(acc[3][j]);
        *(u16x4*)(hTp + (size_t)kblk * 2048 + (f0 + fc + j) * 8 + kslot) = t;
    }
}

// ------------- Kernel 1a: va1 = W^T a1, va2 = W^T a2 ---------------------
__global__ __launch_bounds__(256) void kva(const float* __restrict__ W,
                                           const float* __restrict__ a,
                                           float* __restrict__ va) {
    const int k = threadIdx.x;
    const int b = blockIdx.x;
    const float* av = a + b * 256;
    float s0 = 0.f, s1 = 0.f, s2 = 0.f, s3 = 0.f;
#pragma unroll 8
    for (int f = 0; f < 256; f += 4) {
        s0 = fmaf(av[f],     W[(size_t)f * 256 + k],       s0);
        s1 = fmaf(av[f + 1], W[(size_t)(f + 1) * 256 + k], s1);
        s2 = fmaf(av[f + 2], W[(size_t)(f + 2) * 256 + k], s2);
        s3 = fmaf(av[f + 3], W[(size_t)(f + 3) * 256 + k], s3);
    }
    va[b * 256 + k] = (s0 + s1) + (s2 + s3);
}

// ------------- Kernel 1b: s1 = x@va1, s2 = x@va2 (f32) -------------------
__global__ __launch_bounds__(256) void k1b_s(const float* __restrict__ x,
                                             const float* __restrict__ va,
                                             float* __restrict__ s1,
                                             float* __restrict__ s2) {
    const int tid = threadIdx.x, lane = tid & 63, w = tid >> 6;
    f32x4 a1 = *(const f32x4*)(va + lane * 4);
    f32x4 a2 = *(const f32x4*)(va + 256 + lane * 4);
    const int row0 = blockIdx.x * 32 + w * 8;
#pragma unroll 1
    for (int rr = 0; rr < 8; ++rr) {
        const int row = row0 + rr;
        f32x4 hv = *(const f32x4*)(x + (size_t)row * F_DIM + lane * 4);
        float p1 = hv[0] * a1[0] + hv[1] * a1[1] + hv[2] * a1[2] + hv[3] * a1[3];
        float p2 = hv[0] * a2[0] + hv[1] * a2[1] + hv[2] * a2[2] + hv[3] * a2[3];
#pragma unroll
        for (int o = 32; o; o >>= 1) { p1 += __shfl_xor(p1, o); p2 += __shfl_xor(p2, o); }
        if (lane == 0) { s1[row] = p1; s2[row] = p2; }
    }
}

// ------------- Kernel 1c: M[i] = max over unmasked j of s2[j] ------------
__global__ __launch_bounds__(256) void kmax(const unsigned* __restrict__ mask32,
                                            const float* __restrict__ s2,
                                            float* __restrict__ Mrow) {
    __shared__ float s2l[8192];
    const int tid = threadIdx.x, lane = tid & 63, wv = tid >> 6;
#pragma unroll
    for (int i = 0; i < 8; ++i) {
        const int idx = (i * 256 + tid) * 4;
        *(f32x4*)&s2l[idx] = *(const f32x4*)(s2 + idx);
    }
    __syncthreads();
    const int row = (int)blockIdx.x * 4 + wv;
    const unsigned* __restrict__ mr = mask32 + (size_t)row * 256;
    float vmax = NEG_INF_F;
#pragma unroll 1
    for (int wi = 0; wi < 4; ++wi) {
        const unsigned m = mr[lane * 4 + wi];
        const int kb = (lane * 4 + wi) * 32;
#pragma unroll
        for (int cc = 0; cc < 8; ++cc) {
            const int c = (cc + lane) & 7;
            f32x4 v = *(const f32x4*)&s2l[kb + c * 4];
            const unsigned sh = (unsigned)(c * 4);
            vmax = fmaxf(vmax, ((m >> (sh + 0)) & 1u) ? v[0] : NEG_INF_F);
            vmax = fmaxf(vmax, ((m >> (sh + 1)) & 1u) ? v[1] : NEG_INF_F);
            vmax = fmaxf(vmax, ((m >> (sh + 2)) & 1u) ? v[2] : NEG_INF_F);
            vmax = fmaxf(vmax, ((m >> (sh + 3)) & 1u) ? v[3] : NEG_INF_F);
        }
    }
#pragma unroll
    for (int o = 32; o; o >>= 1) vmax = fmaxf(vmax, __shfl_xor(vmax, o));
    if (lane == 0) Mrow[row] = vmax;
}

// ------------- Kernel 2: fused masked softmax + PV -----------------------
// r10 structure (packed hTp, 2 row-groups/wave, exact precomp max) with:
// (1) raw v_exp_f32 via builtin, (2) native bf16 casts (cvt_pk),
// (3) l computed by a ones-column MFMA (row sums on the matrix pipe).

#define P_ONE(D, SV, BIT, SI, MC)                                             \
    { float t_ = (SI) + (SV); t_ = fmaxf(t_, 0.2f * t_);                      \
      D = fast_exp2(fmaf(((bb_ & (BIT)) ? t_ : NEG_INF_F), LOG2E_F, -(MC))); }

#define RG_STEP(ACC, ACCL, BFR, MW, SI, MC)                                   \
    {                                                                         \
        const unsigned bb_ = ((MW) >> koff) & 0xffu;                          \
        float p0_, p1_, p2_, p3_, p4_, p5_, p6_, p7_;                         \
        P_ONE(p0_, svA_[0], 1u, SI, MC)   P_ONE(p1_, svA_[1], 2u, SI, MC)     \
        P_ONE(p2_, svA_[2], 4u, SI, MC)   P_ONE(p3_, svA_[3], 8u, SI, MC)     \
        P_ONE(p4_, svB_[0], 16u, SI, MC)  P_ONE(p5_, svB_[1], 32u, SI, MC)    \
        P_ONE(p6_, svB_[2], 64u, SI, MC)  P_ONE(p7_, svB_[3], 128u, SI, MC)   \
        s16x8 af_;                                                            \
        af_[0] = f2bf_fast(p0_); af_[1] = f2bf_fast(p1_);                     \
        af_[2] = f2bf_fast(p2_); af_[3] = f2bf_fast(p3_);                     \
        af_[4] = f2bf_fast(p4_); af_[5] = f2bf_fast(p5_);                     \
        af_[6] = f2bf_fast(p6_); af_[7] = f2bf_fast(p7_);                     \
        _Pragma("unroll")                                                     \
        for (int nt_ = 0; nt_ < 8; ++nt_)                                     \
            ACC[nt_] = __builtin_amdgcn_mfma_f32_16x16x32_bf16(af_, BFR[nt_], ACC[nt_], 0, 0, 0); \
        ACCL = __builtin_amdgcn_mfma_f32_16x16x32_bf16(af_, bones, ACCL, 0, 0, 0); \
    }

#define HALF_STEP(BFR, MWA, MWB, K)                                           \
    {                                                                         \
        const f32x4 svA_ = *(const f32x4*)(s2 + (K) + koff);                  \
        const f32x4 svB_ = *(const f32x4*)(s2 + (K) + koff + 4);              \
        RG_STEP(accA, accLA, BFR, MWA, siA, mCA)                              \
        RG_STEP(accB, accLB, BFR, MWB, siB, mCB)                              \
    }

#define LOAD_B(DST, K)                                                        \
    _Pragma("unroll")                                                         \
    for (int nt_ = 0; nt_ < 8; ++nt_)                                         \
        DST[nt_] = *(const s16x8*)(hTp + (unsigned)(((K) >> 3) + kg) * 2048u + vb + (unsigned)(nt_ * 128));

__global__ __launch_bounds__(256) void k2_attn(const unsigned* __restrict__ mask32,
                                               const unsigned short* __restrict__ hTp,
                                               const float* __restrict__ s1,
                                               const float* __restrict__ s2,
                                               const float* __restrict__ Mrow,
                                               float* __restrict__ out) {
    __shared__ float lbuf[4][2][16];            // [wc][rg][row]
    __shared__ float accbuf[3][16][132];        // [wc-1][row][feat] (+4 pad)

    const int tid = threadIdx.x;
    const int lane = tid & 63;
    const int wc = tid >> 6;                    // 0..3 key-chunk
    const int lane15 = lane & 15, kg = lane >> 4, koff = kg * 8;
    const int rowblk = (int)blockIdx.x >> 1;
    const int fh = (int)blockIdx.x & 1;
    const int row0 = rowblk * 32;
    const int mrowA = row0 + lane15, mrowB = row0 + 16 + lane15;
    const int fb = fh * 128;
    const int kbase = wc * 2048;
    const float siA = s1[mrowA], siB = s1[mrowB];
    const float tmxA = siA + Mrow[mrowA], tmxB = siB + Mrow[mrowB];
    const float mCA = fmaxf(tmxA, 0.2f * tmxA) * LOG2E_F;
    const float mCB = fmaxf(tmxB, 0.2f * tmxB) * LOG2E_F;
    const unsigned* __restrict__ mA32 = mask32 + (size_t)mrowA * 256;
    const unsigned* __restrict__ mB32 = mask32 + (size_t)mrowB * 256;

    f32x4 accA[8], accB[8], accLA, accLB;
#pragma unroll
    for (int nt = 0; nt < 8; ++nt) {
        f32x4 z = {0.f, 0.f, 0.f, 0.f};
        accA[nt] = z; accB[nt] = z;
    }
    { f32x4 z = {0.f, 0.f, 0.f, 0.f}; accLA = z; accLB = z; }

    s16x8 bones;
#pragma unroll
    for (int j = 0; j < 8; ++j) bones[j] = (short)0x3F80;   // bf16 1.0

    const unsigned vb = (unsigned)(fb + lane15) * 8u;

    s16x8 bA[8], bB[8];
    LOAD_B(bA, kbase)
    unsigned mwA = mA32[kbase >> 5], mwB = mB32[kbase >> 5];

#pragma unroll 1
    for (int it = 0; it < 64; it += 2) {
        const int k0 = kbase + it * 32;
        const int k1 = k0 + 32;
        const int k2n = (it + 2 < 64) ? (k0 + 64) : kbase;   // wrap: loaded, unused

        LOAD_B(bB, k1)
        const unsigned mwnA = mA32[k1 >> 5], mwnB = mB32[k1 >> 5];

        HALF_STEP(bA, mwA, mwB, k0);

        LOAD_B(bA, k2n)
        mwA = mA32[k2n >> 5]; mwB = mB32[k2n >> 5];

        HALF_STEP(bB, mwnA, mwnB, k1);
    }

    // l: ones-MFMA already reduced over keys; every D column holds the row sum.
    // Lane with lane15==0 (col 0) owns rows kg*4..kg*4+3 in regs 0..3.
    if (lane15 == 0) {
#pragma unroll
        for (int r = 0; r < 4; ++r) {
            lbuf[wc][0][kg * 4 + r] = accLA[r];
            lbuf[wc][1][kg * 4 + r] = accLB[r];
        }
    }

    // ---- phase A: merge + write row-group 0 ----
    if (wc > 0) {
#pragma unroll
        for (int r = 0; r < 4; ++r)
#pragma unroll
            for (int nt = 0; nt < 8; ++nt)
                accbuf[wc - 1][kg * 4 + r][nt * 16 + lane15] = accA[nt][r];
    }
    __syncthreads();
    if (wc == 0) {
#pragma unroll
        for (int r = 0; r < 4; ++r) {
            const int dr = kg * 4 + r;
            const float lt = (lbuf[0][0][dr] + lbuf[1][0][dr]) + (lbuf[2][0][dr] + lbuf[3][0][dr]);
            const float inv = 1.0f / lt;
            float* orow_p = out + (size_t)(row0 + dr) * F_DIM + fb + lane15;
#pragma unroll
            for (int nt = 0; nt < 8; ++nt) {
                const float v = accA[nt][r] + accbuf[0][dr][nt * 16 + lane15]
                              + accbuf[1][dr][nt * 16 + lane15]
                              + accbuf[2][dr][nt * 16 + lane15];
                orow_p[nt * 16] = v * inv;
            }
        }
    }
    __syncthreads();

    // ---- phase B: merge + write row-group 1 ----
    if (wc > 0) {
#pragma unroll
        for (int r = 0; r < 4; ++r)
#pragma unroll
            for (int nt = 0; nt < 8; ++nt)
                accbuf[wc - 1][kg * 4 + r][nt * 16 + lane15] = accB[nt][r];
    }
    __syncthreads();
    if (wc == 0) {
#pragma unroll
        for (int r = 0; r < 4; ++r) {
            const int dr = kg * 4 + r;
            const float lt = (lbuf[0][1][dr] + lbuf[1][1][dr]) + (lbuf[2][1][dr] + lbuf[3][1][dr]);
            const float inv = 1.0f / lt;
            float* orow_p = out + (size_t)(row0 + 16 + dr) * F_DIM + fb + lane15;
#pragma unroll
            for (int nt = 0; nt < 8; ++nt) {
                const float v = accB[nt][r] + accbuf[0][dr][nt * 16 + lane15]
                              + accbuf[1][dr][nt * 16 + lane15]
                              + accbuf[2][dr][nt * 16 + lane15];
                orow_p[nt * 16] = v * inv;
            }
        }
    }
}

extern "C" void kernel_launch(void* const* d_in, const int* in_sizes, int n_in,
                              void* d_out, int out_size, void* d_ws, size_t ws_size,
                              hipStream_t stream) {
    (void)in_sizes; (void)n_in; (void)out_size; (void)ws_size;
    const float* x  = (const float*)d_in[0];
    const int*  adj = (const int*)d_in[1];
    const float* W  = (const float*)d_in[2];
    const float* a  = (const float*)d_in[3];
    float* out = (float*)d_out;
    char* ws = (char*)d_ws;
    // total ws use: 12.13 MB
    unsigned short* hTp = (unsigned short*)ws;                      // 4 MB  packed bf16
    float* s1 = (float*)(ws + (4 << 20));                           // 32 KB
    float* s2 = (float*)(ws + (4 << 20) + (32 << 10));              // 32 KB
    float* va = (float*)(ws + (4 << 20) + (64 << 10));              // 2 KB
    float* Mr = (float*)(ws + (4 << 20) + (96 << 10));              // 32 KB
    unsigned* mk = (unsigned*)(ws + (4 << 20) + (128 << 10));       // 8 MB

    k0_pack<<<2048, 256, 0, stream>>>(adj, mk);
    k1_gemm<<<512, 256, 0, stream>>>(x, W, hTp);
    kva<<<2, 256, 0, stream>>>(W, a, va);
    k1b_s<<<256, 256, 0, stream>>>(x, va, s1, s2);
    kmax<<<2048, 256, 0, stream>>>(mk, s2, Mr);
    k2_attn<<<512, 256, 0, stream>>>(mk, hTp, s1, s2, Mr, out);
}